// Round 10
// baseline (46.907 us; speedup 1.0000x reference)
//
#include <hip/hip_runtime.h>

#define L_N    50000
#define K_DIM  512
#define GRID1  256             // one 1024-thread block per CU
#define NGRP   3125            // 50000 rows / 16 rows per wave-group
#define NSLOT  64              // atomic spread slots
#define SB()   __builtin_amdgcn_sched_barrier(0)
// ws: float[33][64] atomic accumulators + int counter at ws[33*64] (zeroed per call)

typedef __attribute__((ext_vector_type(8))) short bf16x8;
typedef __attribute__((ext_vector_type(4))) float f32x4;

// split 8 f32 into truncated-bf16 hi + bf16(residual) lo  (validated R2-R9: absmax 0.0)
__device__ __forceinline__ void split8(float4 a, float4 b, bf16x8& hi, bf16x8& lo) {
    float v[8] = {a.x, a.y, a.z, a.w, b.x, b.y, b.z, b.w};
    #pragma unroll
    for (int j = 0; j < 8; ++j) {
        unsigned u  = __float_as_uint(v[j]);
        unsigned hb = u & 0xFFFF0000u;
        float    lf = v[j] - __uint_as_float(hb);
        hi[j] = (short)(hb >> 16);
        lo[j] = (short)(__float_as_uint(lf) >> 16);
    }
}

__global__ __launch_bounds__(1024) void k_fused(
    const float* __restrict__ other,   // [L][512]
    const float* __restrict__ W12,     // [32][512]
    const float* __restrict__ b12,     // [32]
    const float* __restrict__ Wa,      // [96]
    const float* __restrict__ inputs,  // [256]
    const float* __restrict__ act_idx, // [64]
    const float* __restrict__ W11, const float* __restrict__ b11,
    const float* __restrict__ Wao, const float* __restrict__ bao,
    const float* __restrict__ W2,  const float* __restrict__ b2,
    const float* __restrict__ W3,  const float* __restrict__ b3,
    float* __restrict__ ws,
    float* __restrict__ out)           // [33]: r, samples[32]
{
    // W12 pre-split hi/lo, frag unit r = kc*4+g (k-permuted, validated R4-R9),
    // slot-swizzled: phys = r*32 + (ch ^ (r&31))
    __shared__ short whi[16384];       // 32 KB
    __shared__ short wlo[16384];       // 32 KB
    __shared__ float sbuf[16][34];
    __shared__ int   elect;

    const int tid  = threadIdx.x;
    const int lane = tid & 63;
    const int wv   = tid >> 6;         // 0..15
    const int cl   = lane & 15;
    const int g    = lane >> 4;

    // ---- one-time per CU: W12 -> LDS pre-split (2 frag-units per thread) ----
    #pragma unroll
    for (int c2 = 0; c2 < 2; ++c2) {
        const int u  = tid + c2 * 1024;          // unit: ch = u>>6, r = u&63
        const int ch = u >> 6, r = u & 63;       // r = kc*4+gg
        const float* wp = W12 + (size_t)ch * K_DIM + (r >> 2) * 32 + (r & 3) * 4;
        const float4 f0 = *(const float4*)wp;
        const float4 f1 = *(const float4*)(wp + 16);
        bf16x8 h8, l8; split8(f0, f1, h8, l8);
        const int p = (r * 32 + (ch ^ (r & 31))) * 8;
        *(bf16x8*)&whi[p] = h8;
        *(bf16x8*)&wlo[p] = l8;
    }
    __syncthreads();

    float rps = 0.f, rm0 = 0.f, rm1 = 0.f;       // per-lane partials
    const int wid = blockIdx.x * 16 + wv;        // global wave id = group id

    if (wid < NGRP) {
        const float b0 = b12[cl],     b1 = b12[16 + cl];
        const float w0 = Wa[64 + cl], w1 = Wa[80 + cl];  // shift-invariance: rx·Wa, ba dropped

        // lane (g,cl): row = wid*16+cl (always < 50000), k-window g*4 within each 16
        const float* xp = other + (size_t)(wid * 16 + cl) * K_DIM + (g << 2);
        float4 Q0[4], Q1[4];                     // 32 VGPR total: no spill at cap 128

        #define ISSUE4(dst, q) do {                                            \
            _Pragma("unroll")                                                  \
            for (int i = 0; i < 4; ++i)                                        \
                dst[i] = *(const float4*)(xp + (q) * 64 + (i >> 1) * 32 + (i & 1) * 16); \
        } while (0)

        f32x4 acc0 = {0.f,0.f,0.f,0.f}, acc1 = {0.f,0.f,0.f,0.f};

        #define CONSUME4(buf, q) do {                                          \
            _Pragma("unroll")                                                  \
            for (int kk = 0; kk < 2; ++kk) {                                   \
                const int kc = (q) * 2 + kk;                                   \
                bf16x8 ah, al; split8(buf[kk * 2], buf[kk * 2 + 1], ah, al);   \
                const int r  = kc * 4 + g;                                     \
                const int u0 = (r * 32 + (cl ^ (r & 31))) * 8;                 \
                const bf16x8 bh0 = *(const bf16x8*)&whi[u0];                   \
                const bf16x8 bl0 = *(const bf16x8*)&wlo[u0];                   \
                const bf16x8 bh1 = *(const bf16x8*)&whi[u0 ^ 128];             \
                const bf16x8 bl1 = *(const bf16x8*)&wlo[u0 ^ 128];             \
                acc0 = __builtin_amdgcn_mfma_f32_16x16x32_bf16(ah, bh0, acc0, 0, 0, 0); \
                acc0 = __builtin_amdgcn_mfma_f32_16x16x32_bf16(al, bh0, acc0, 0, 0, 0); \
                acc0 = __builtin_amdgcn_mfma_f32_16x16x32_bf16(ah, bl0, acc0, 0, 0, 0); \
                acc1 = __builtin_amdgcn_mfma_f32_16x16x32_bf16(ah, bh1, acc1, 0, 0, 0); \
                acc1 = __builtin_amdgcn_mfma_f32_16x16x32_bf16(al, bh1, acc1, 0, 0, 0); \
                acc1 = __builtin_amdgcn_mfma_f32_16x16x32_bf16(ah, bl1, acc1, 0, 0, 0); \
            }                                                                  \
        } while (0)

        // rolling 2-deep quarter pipeline (validated R9: no spills)
        ISSUE4(Q0, 0); SB();
        ISSUE4(Q1, 1); SB();
        CONSUME4(Q0, 0); ISSUE4(Q0, 2); SB();
        CONSUME4(Q1, 1); ISSUE4(Q1, 3); SB();
        CONSUME4(Q0, 2); ISSUE4(Q0, 4); SB();
        CONSUME4(Q1, 3); ISSUE4(Q1, 5); SB();
        CONSUME4(Q0, 4); ISSUE4(Q0, 6); SB();
        CONSUME4(Q1, 5); ISSUE4(Q1, 7); SB();
        CONSUME4(Q0, 6);
        CONSUME4(Q1, 7);

        // ---- epilogue (validated): C row=(g*4+i), col=cl ----
        float e0[4], e1[4], s4[4];
        #pragma unroll
        for (int i = 0; i < 4; ++i) {
            e0[i] = acc0[i] + b0;
            e1[i] = acc1[i] + b1;
            s4[i] = fmaxf(e0[i], 0.f) * w0 + fmaxf(e1[i], 0.f) * w1;
        }
        #pragma unroll
        for (int d = 1; d < 16; d <<= 1) {
            #pragma unroll
            for (int i = 0; i < 4; ++i) s4[i] += __shfl_xor(s4[i], d);
        }
        #pragma unroll
        for (int i = 0; i < 4; ++i) {
            const float p = __expf(s4[i]);       // all rows valid: 3125*16 == 50000
            rps += p;
            rm0 = fmaf(p, e0[i], rm0);
            rm1 = fmaf(p, e1[i], rm1);
        }
    }

    // ---- block reduce + agent-scope atomic accumulate (proven R3-R5 tail) ----
    rps += __shfl_xor(rps, 16); rps += __shfl_xor(rps, 32);
    rm0 += __shfl_xor(rm0, 16); rm0 += __shfl_xor(rm0, 32);
    rm1 += __shfl_xor(rm1, 16); rm1 += __shfl_xor(rm1, 32);
    if (lane == 0)  sbuf[wv][0] = rps;
    if (lane < 16) { sbuf[wv][1 + cl] = rm0; sbuf[wv][17 + cl] = rm1; }
    __syncthreads();
    if (wv == 0 && lane < 33) {
        float v = 0.f;
        #pragma unroll
        for (int s = 0; s < 16; ++s) v += sbuf[s][lane];
        atomicAdd(ws + lane * NSLOT + (blockIdx.x & (NSLOT - 1)), v);
        __threadfence();
    }
    __syncthreads();                   // waits vmcnt(0): RMWs complete at coherent point
    if (tid == 0) {
        const int v = __hip_atomic_fetch_add((int*)(ws + 33 * NSLOT), 1,
                                             __ATOMIC_ACQ_REL, __HIP_MEMORY_SCOPE_AGENT);
        elect = (v == GRID1 - 1);
    }
    __syncthreads();
    if (!elect) return;

    // ---- final MLP inside the last block (no second dispatch) ----
    __shared__ float xsin[320];
    __shared__ float wsl[33];
    __shared__ float rm[32], z[32], xcat[96], h64[64];
    __shared__ int   amax;

    const int t = tid, hh = t >> 2, q = t & 3;
    if (t < 132) {                     // coherent atomic reads, 16 slots each
        const int c = t >> 2, seg = t & 3;
        float v = 0.f;
        #pragma unroll
        for (int i = 0; i < 16; ++i) v += atomicAdd(ws + c * NSLOT + seg * 16 + i, 0.f);
        v += __shfl_xor(v, 1);
        v += __shfl_xor(v, 2);
        if (seg == 0) wsl[c] = v;
    }
    if (t < 256) xsin[t] = inputs[t];
    if (t < 64)  xsin[256 + t] = act_idx[t];
    __syncthreads();

    if (t < 32) rm[t] = fmaxf(wsl[1 + t] / wsl[0], 0.f);

    float bp = 0.f;
    if (t < 256) {                     // wave-uniform guard (waves 4..15 skip)
        const float4* wrow = (const float4*)(W11 + hh * 320 + q * 80);
        #pragma unroll
        for (int i = 0; i < 20; ++i) {
            const float4 f = wrow[i];
            const int k = q * 80 + i * 4;
            bp = fmaf(f.x, xsin[k], bp);
            bp = fmaf(f.y, xsin[k + 1], bp);
            bp = fmaf(f.z, xsin[k + 2], bp);
            bp = fmaf(f.w, xsin[k + 3], bp);
        }
        bp += __shfl_xor(bp, 1);
        bp += __shfl_xor(bp, 2);
    }
    __syncthreads();

    if (t < 32) {
        float zz = bao[t];
        for (int d = 0; d < 32; ++d) zz = fmaf(Wao[t * 32 + d], rm[d], zz);
        z[t] = zz;
    }
    __syncthreads();
    if (t == 0) {
        int bi = 0; float bv = z[0];
        for (int c = 1; c < 32; ++c) { if (z[c] > bv) { bv = z[c]; bi = c; } }
        amax = bi;                                    // first-max, matches jnp.argmax
    }
    __syncthreads();
    if (t < 256 && q == 0) xcat[hh] = fmaxf(bp + b11[hh], 0.f);
    if (t < 32) xcat[64 + t] = (t == amax) ? 1.f : 0.f;   // one_hot_st == samples
    __syncthreads();

    float dp = 0.f;
    if (t < 256) {
        for (int i = 0; i < 24; ++i) {
            const int k = q * 24 + i;
            dp = fmaf(W2[hh * 96 + k], xcat[k], dp);
        }
        dp += __shfl_xor(dp, 1);
        dp += __shfl_xor(dp, 2);
        if (q == 0) h64[hh] = fmaxf(dp + b2[hh], 0.f);
    }
    __syncthreads();

    if (t == 0) {
        float r = b3[0];
        for (int i = 0; i < 64; ++i) r = fmaf(W3[i], h64[i], r);
        out[0] = r;
    }
    if (t < 32) out[1 + t] = (t == amax) ? 1.f : 0.f;
}

extern "C" void kernel_launch(void* const* d_in, const int* in_sizes, int n_in,
                              void* d_out, int out_size, void* d_ws, size_t ws_size,
                              hipStream_t stream) {
    const float* inputs  = (const float*)d_in[0];
    const float* act_idx = (const float*)d_in[1];
    const float* other   = (const float*)d_in[2];
    const float* W11     = (const float*)d_in[3];
    const float* b11     = (const float*)d_in[4];
    const float* W12     = (const float*)d_in[5];
    const float* b12     = (const float*)d_in[6];
    const float* Wa      = (const float*)d_in[7];
    // d_in[8] = ba : unused (softmax shift-invariant)
    const float* Wao     = (const float*)d_in[9];
    const float* bao     = (const float*)d_in[10];
    const float* W2      = (const float*)d_in[11];
    const float* b2      = (const float*)d_in[12];
    const float* W3      = (const float*)d_in[13];
    const float* b3      = (const float*)d_in[14];
    float* ws = (float*)d_ws;

    hipMemsetAsync(ws, 0, (33 * NSLOT + 1) * sizeof(float), stream);
    k_fused<<<GRID1, 1024, 0, stream>>>(other, W12, b12, Wa,
                                        inputs, act_idx, W11, b11,
                                        Wao, bao, W2, b2, W3, b3,
                                        ws, (float*)d_out);
}

// Round 11
// 32.330 us; speedup vs baseline: 1.4509x; 1.4509x over previous
//
#include <hip/hip_runtime.h>

#define L_N    50000
#define K_DIM  512
#define GRID1  256             // one 1024-thread block per CU
#define NGRP   3125            // 50000 rows / 16 rows per wave-group
#define SB()   __builtin_amdgcn_sched_barrier(0)
// ws layout: float[33][256]  (channel-major -> k_final reads contiguous rows)

typedef __attribute__((ext_vector_type(8))) short bf16x8;
typedef __attribute__((ext_vector_type(4))) float f32x4;

// split 8 f32 into truncated-bf16 hi + bf16(residual) lo  (validated R2-R10: absmax 0.0)
__device__ __forceinline__ void split8(float4 a, float4 b, bf16x8& hi, bf16x8& lo) {
    float v[8] = {a.x, a.y, a.z, a.w, b.x, b.y, b.z, b.w};
    #pragma unroll
    for (int j = 0; j < 8; ++j) {
        unsigned u  = __float_as_uint(v[j]);
        unsigned hb = u & 0xFFFF0000u;
        float    lf = v[j] - __uint_as_float(hb);
        hi[j] = (short)(hb >> 16);
        lo[j] = (short)(__float_as_uint(lf) >> 16);
    }
}

__global__ __launch_bounds__(1024) void k_part(
    const float* __restrict__ other,   // [L][512]
    const float* __restrict__ W12,     // [32][512]
    const float* __restrict__ b12,     // [32]
    const float* __restrict__ Wa,      // [96]
    float* __restrict__ ws)            // [33][256]
{
    // W12 pre-split hi/lo, frag unit r = kc*4+g (k-permuted, validated R4-R10),
    // slot-swizzled: phys = r*32 + (ch ^ (r&31))
    __shared__ short whi[16384];       // 32 KB
    __shared__ short wlo[16384];       // 32 KB
    __shared__ float sbuf[16][34];

    const int tid  = threadIdx.x;
    const int lane = tid & 63;
    const int wv   = tid >> 6;         // 0..15
    const int cl   = lane & 15;
    const int g    = lane >> 4;

    // ---- one-time per CU: W12 -> LDS pre-split (2 frag-units per thread) ----
    #pragma unroll
    for (int c2 = 0; c2 < 2; ++c2) {
        const int u  = tid + c2 * 1024;          // unit: ch = u>>6, r = u&63
        const int ch = u >> 6, r = u & 63;       // r = kc*4+gg
        const float* wp = W12 + (size_t)ch * K_DIM + (r >> 2) * 32 + (r & 3) * 4;
        const float4 f0 = *(const float4*)wp;
        const float4 f1 = *(const float4*)(wp + 16);
        bf16x8 h8, l8; split8(f0, f1, h8, l8);
        const int p = (r * 32 + (ch ^ (r & 31))) * 8;
        *(bf16x8*)&whi[p] = h8;
        *(bf16x8*)&wlo[p] = l8;
    }
    __syncthreads();

    float rps = 0.f, rm0 = 0.f, rm1 = 0.f;       // per-lane partials
    const int wid = blockIdx.x * 16 + wv;        // global wave id = group id

    if (wid < NGRP) {
        const float b0 = b12[cl],     b1 = b12[16 + cl];
        const float w0 = Wa[64 + cl], w1 = Wa[80 + cl];  // shift-invariance: rx·Wa, ba dropped

        // lane (g,cl): row = wid*16+cl (always < 50000), k-window g*4 within each 16
        const float* xp = other + (size_t)(wid * 16 + cl) * K_DIM + (g << 2);

        // asm-pinned load batches: compiler CANNOT fuse issue into consume (R10: VGPR 44
        // proved source-level batches get flattened to 0-deep).  All 32 loads use one
        // base VGPR-pair + offset: immediates (max 1984 <= 4095).
        float4 a0, a1, a2, a3, b0v, b1v, b2v, b3v, c0v, c1v, c2v, c3v, d0v, d1v, d2v, d3v;

        #define GLD(dst, OFF)                                                  \
            asm volatile("global_load_dwordx4 %0, %1, off offset:" OFF        \
                         : "=v"(dst) : "v"(xp) : "memory")
        #define GLDQ(x0,x1,x2,x3, O0,O1,O2,O3) do {                            \
            GLD(x0, O0); GLD(x1, O1); GLD(x2, O2); GLD(x3, O3);                \
        } while (0)
        #define VMW(N) do {                                                    \
            asm volatile("s_waitcnt vmcnt(" #N ")" ::: "memory");              \
            __builtin_amdgcn_sched_barrier(0);   /* rule 18: no hoist past wait */ \
        } while (0)

        f32x4 acc0 = {0.f,0.f,0.f,0.f}, acc1 = {0.f,0.f,0.f,0.f};

        #define CONSH(xlo, xhi, KC) do {                                       \
            bf16x8 ah, al; split8(xlo, xhi, ah, al);                           \
            const int r_  = (KC) * 4 + g;                                      \
            const int u0_ = (r_ * 32 + (cl ^ (r_ & 31))) * 8;                  \
            const bf16x8 bh0 = *(const bf16x8*)&whi[u0_];                      \
            const bf16x8 bl0 = *(const bf16x8*)&wlo[u0_];                      \
            const bf16x8 bh1 = *(const bf16x8*)&whi[u0_ ^ 128];                \
            const bf16x8 bl1 = *(const bf16x8*)&wlo[u0_ ^ 128];                \
            acc0 = __builtin_amdgcn_mfma_f32_16x16x32_bf16(ah, bh0, acc0, 0, 0, 0); \
            acc0 = __builtin_amdgcn_mfma_f32_16x16x32_bf16(al, bh0, acc0, 0, 0, 0); \
            acc0 = __builtin_amdgcn_mfma_f32_16x16x32_bf16(ah, bl0, acc0, 0, 0, 0); \
            acc1 = __builtin_amdgcn_mfma_f32_16x16x32_bf16(ah, bh1, acc1, 0, 0, 0); \
            acc1 = __builtin_amdgcn_mfma_f32_16x16x32_bf16(al, bh1, acc1, 0, 0, 0); \
            acc1 = __builtin_amdgcn_mfma_f32_16x16x32_bf16(ah, bl1, acc1, 0, 0, 0); \
        } while (0)
        #define CONSQ(x0,x1,x2,x3, QQ) do {                                    \
            CONSH(x0, x1, 2*(QQ));                                             \
            CONSH(x2, x3, 2*(QQ)+1);                                           \
        } while (0)

        // prologue: fill 4 quarter-buffers (16 loads in flight)
        GLDQ(a0,a1,a2,a3,   "0",   "64",  "128",  "192");
        GLDQ(b0v,b1v,b2v,b3v, "256",  "320",  "384",  "448");
        GLDQ(c0v,c1v,c2v,c3v, "512",  "576",  "640",  "704");
        GLDQ(d0v,d1v,d2v,d3v, "768",  "832",  "896",  "960");
        // steady state: 12-16 loads outstanding, consume oldest, reissue
        VMW(12); CONSQ(a0,a1,a2,a3, 0);  GLDQ(a0,a1,a2,a3, "1024","1088","1152","1216");
        VMW(12); CONSQ(b0v,b1v,b2v,b3v, 1); GLDQ(b0v,b1v,b2v,b3v, "1280","1344","1408","1472");
        VMW(12); CONSQ(c0v,c1v,c2v,c3v, 2); GLDQ(c0v,c1v,c2v,c3v, "1536","1600","1664","1728");
        VMW(12); CONSQ(d0v,d1v,d2v,d3v, 3); GLDQ(d0v,d1v,d2v,d3v, "1792","1856","1920","1984");
        // drain
        VMW(12); CONSQ(a0,a1,a2,a3, 4);
        VMW(8);  CONSQ(b0v,b1v,b2v,b3v, 5);
        VMW(4);  CONSQ(c0v,c1v,c2v,c3v, 6);
        VMW(0);  CONSQ(d0v,d1v,d2v,d3v, 7);

        // ---- epilogue (validated): C row=(g*4+i), col=cl ----
        float e0[4], e1[4], s4[4];
        #pragma unroll
        for (int i = 0; i < 4; ++i) {
            e0[i] = acc0[i] + b0;
            e1[i] = acc1[i] + b1;
            s4[i] = fmaxf(e0[i], 0.f) * w0 + fmaxf(e1[i], 0.f) * w1;
        }
        #pragma unroll
        for (int d = 1; d < 16; d <<= 1) {
            #pragma unroll
            for (int i = 0; i < 4; ++i) s4[i] += __shfl_xor(s4[i], d);
        }
        #pragma unroll
        for (int i = 0; i < 4; ++i) {
            const float p = __expf(s4[i]);       // all rows valid: 3125*16 == 50000
            rps += p;
            rm0 = fmaf(p, e0[i], rm0);
            rm1 = fmaf(p, e1[i], rm1);
        }
    }

    // ---- block reduce: 33 plain stores (channel-major) ----
    rps += __shfl_xor(rps, 16); rps += __shfl_xor(rps, 32);
    rm0 += __shfl_xor(rm0, 16); rm0 += __shfl_xor(rm0, 32);
    rm1 += __shfl_xor(rm1, 16); rm1 += __shfl_xor(rm1, 32);
    if (lane == 0)  sbuf[wv][0] = rps;
    if (lane < 16) { sbuf[wv][1 + cl] = rm0; sbuf[wv][17 + cl] = rm1; }
    __syncthreads();
    if (wv == 0 && lane < 33) {
        float v = 0.f;
        #pragma unroll
        for (int s = 0; s < 16; ++s) v += sbuf[s][lane];
        ws[lane * GRID1 + blockIdx.x] = v;
    }
}

__global__ __launch_bounds__(256) void k_final(
    const float* __restrict__ ws,       // [33][256]
    const float* __restrict__ inputs,   // [256]
    const float* __restrict__ act_idx,  // [64]
    const float* __restrict__ W11, const float* __restrict__ b11,
    const float* __restrict__ Wao, const float* __restrict__ bao,
    const float* __restrict__ W2,  const float* __restrict__ b2,
    const float* __restrict__ W3,  const float* __restrict__ b3,
    float* __restrict__ out)            // [33]: r, samples[32]
{
    __shared__ float xsin[320];
    __shared__ float wsl[33];
    __shared__ float rm[32], z[32], xcat[96], h64[64];
    __shared__ int   amax;

    const int t = threadIdx.x, hh = t >> 2, q = t & 3;

    // parallel vectorized cross-block reduction: 132 threads, 64 floats each
    if (t < 132) {
        const int c = t >> 2, seg = t & 3;
        const float4* p = (const float4*)(ws + c * GRID1 + seg * 64);
        float v = 0.f;
        #pragma unroll
        for (int i = 0; i < 16; ++i) { const float4 f = p[i]; v += f.x + f.y + f.z + f.w; }
        v += __shfl_xor(v, 1);
        v += __shfl_xor(v, 2);
        if (seg == 0) wsl[c] = v;
    }
    // stage x_in = [inputs ; act_idx] in LDS
    xsin[t] = inputs[t];
    if (t < 64) xsin[256 + t] = act_idx[t];
    __syncthreads();

    if (t < 32) rm[t] = fmaxf(wsl[1 + t] / wsl[0], 0.f);

    // input_x: 4 threads per output h, 80 k each, float4 W11 loads
    float bp = 0.f;
    {
        const float4* wrow = (const float4*)(W11 + hh * 320 + q * 80);
        #pragma unroll
        for (int i = 0; i < 20; ++i) {
            const float4 f = wrow[i];
            const int k = q * 80 + i * 4;
            bp = fmaf(f.x, xsin[k], bp);
            bp = fmaf(f.y, xsin[k + 1], bp);
            bp = fmaf(f.z, xsin[k + 2], bp);
            bp = fmaf(f.w, xsin[k + 3], bp);
        }
    }
    bp += __shfl_xor(bp, 1);
    bp += __shfl_xor(bp, 2);
    __syncthreads();

    if (t < 32) {
        float zz = bao[t];
        for (int d = 0; d < 32; ++d) zz = fmaf(Wao[t * 32 + d], rm[d], zz);
        z[t] = zz;
    }
    __syncthreads();
    if (t == 0) {
        int bi = 0; float bv = z[0];
        for (int c = 1; c < 32; ++c) { if (z[c] > bv) { bv = z[c]; bi = c; } }
        amax = bi;                                    // first-max, matches jnp.argmax
    }
    __syncthreads();
    if (q == 0) xcat[hh] = fmaxf(bp + b11[hh], 0.f);
    if (t < 32) xcat[64 + t] = (t == amax) ? 1.f : 0.f;   // one_hot_st == samples
    __syncthreads();

    float dp = 0.f;
    for (int i = 0; i < 24; ++i) {
        const int k = q * 24 + i;
        dp = fmaf(W2[hh * 96 + k], xcat[k], dp);
    }
    dp += __shfl_xor(dp, 1);
    dp += __shfl_xor(dp, 2);
    if (q == 0) h64[hh] = fmaxf(dp + b2[hh], 0.f);
    __syncthreads();

    if (t == 0) {
        float r = b3[0];
        for (int i = 0; i < 64; ++i) r = fmaf(W3[i], h64[i], r);
        out[0] = r;
    }
    if (t < 32) out[1 + t] = (t == amax) ? 1.f : 0.f;
}

extern "C" void kernel_launch(void* const* d_in, const int* in_sizes, int n_in,
                              void* d_out, int out_size, void* d_ws, size_t ws_size,
                              hipStream_t stream) {
    const float* inputs  = (const float*)d_in[0];
    const float* act_idx = (const float*)d_in[1];
    const float* other   = (const float*)d_in[2];
    const float* W11     = (const float*)d_in[3];
    const float* b11     = (const float*)d_in[4];
    const float* W12     = (const float*)d_in[5];
    const float* b12     = (const float*)d_in[6];
    const float* Wa      = (const float*)d_in[7];
    // d_in[8] = ba : unused (softmax shift-invariant)
    const float* Wao     = (const float*)d_in[9];
    const float* bao     = (const float*)d_in[10];
    const float* W2      = (const float*)d_in[11];
    const float* b2      = (const float*)d_in[12];
    const float* W3      = (const float*)d_in[13];
    const float* b3      = (const float*)d_in[14];
    float* ws = (float*)d_ws;

    // every ws slot k_final reads is written by k_part -> no memset needed
    k_part<<<GRID1, 1024, 0, stream>>>(other, W12, b12, Wa, ws);
    k_final<<<1, 256, 0, stream>>>(ws, inputs, act_idx, W11, b11,
                                   Wao, bao, W2, b2, W3, b3, (float*)d_out);
}